// Round 5
// baseline (205.687 us; speedup 1.0000x reference)
//
#include <hip/hip_runtime.h>
#include <hip/hip_bf16.h>
#include <math.h>

typedef float f32x4 __attribute__((ext_vector_type(4)));
typedef int   i32x4 __attribute__((ext_vector_type(4)));
typedef int   i32x8 __attribute__((ext_vector_type(8)));

#define BSZ 8192
#define DIM 2048
#define NTILE 64          // 8192 / 128 tiles per side
#define BK 128            // K elements per step (one MX mfma)
#define KSTEPS 16         // 2048 / 128

// MX e8m0 scale byte for 2^-4 (we pre-scale inputs by 16): 127-4 = 123.
#define SCALE_I32 0x7B7B7B7B

// ---------- kernel 1: fused normalize -> fp8(x*16), diag cos (fp32) ----------
__global__ void __launch_bounds__(256) k_prep(const float* __restrict__ X,
                                              const float* __restrict__ Y,
                                              unsigned char* __restrict__ Xq,
                                              unsigned char* __restrict__ Yq,
                                              float* __restrict__ dg) {
  const int row = blockIdx.x;
  const int tid = threadIdx.x;
  const float4* xp = (const float4*)(X + (size_t)row * DIM);
  const float4* yp = (const float4*)(Y + (size_t)row * DIM);
  float4 x0 = xp[tid * 2], x1 = xp[tid * 2 + 1];
  float4 y0 = yp[tid * 2], y1 = yp[tid * 2 + 1];
  float sxx = x0.x*x0.x + x0.y*x0.y + x0.z*x0.z + x0.w*x0.w
            + x1.x*x1.x + x1.y*x1.y + x1.z*x1.z + x1.w*x1.w;
  float syy = y0.x*y0.x + y0.y*y0.y + y0.z*y0.z + y0.w*y0.w
            + y1.x*y1.x + y1.y*y1.y + y1.z*y1.z + y1.w*y1.w;
  float sxy = x0.x*y0.x + x0.y*y0.y + x0.z*y0.z + x0.w*y0.w
            + x1.x*y1.x + x1.y*y1.y + x1.z*y1.z + x1.w*y1.w;
#pragma unroll
  for (int m = 32; m >= 1; m >>= 1) {
    sxx += __shfl_xor(sxx, m);
    syy += __shfl_xor(syy, m);
    sxy += __shfl_xor(sxy, m);
  }
  __shared__ float sh[3][4];
  if ((tid & 63) == 0) {
    sh[0][tid >> 6] = sxx; sh[1][tid >> 6] = syy; sh[2][tid >> 6] = sxy;
  }
  __syncthreads();
  float xx = sh[0][0] + sh[0][1] + sh[0][2] + sh[0][3];
  float yy = sh[1][0] + sh[1][1] + sh[1][2] + sh[1][3];
  float xy = sh[2][0] + sh[2][1] + sh[2][2] + sh[2][3];
  float nx = fmaxf(sqrtf(xx), 1e-8f);
  float ny = fmaxf(sqrtf(yy), 1e-8f);
  float ix = 16.0f / nx, iy = 16.0f / ny;   // x16 pre-scale into e4m3 sweet spot
  float vx[8] = {x0.x, x0.y, x0.z, x0.w, x1.x, x1.y, x1.z, x1.w};
  float vy[8] = {y0.x, y0.y, y0.z, y0.w, y1.x, y1.y, y1.z, y1.w};
  int px0 = __builtin_amdgcn_cvt_pk_fp8_f32(vx[0]*ix, vx[1]*ix, 0, false);
  px0     = __builtin_amdgcn_cvt_pk_fp8_f32(vx[2]*ix, vx[3]*ix, px0, true);
  int px1 = __builtin_amdgcn_cvt_pk_fp8_f32(vx[4]*ix, vx[5]*ix, 0, false);
  px1     = __builtin_amdgcn_cvt_pk_fp8_f32(vx[6]*ix, vx[7]*ix, px1, true);
  int py0 = __builtin_amdgcn_cvt_pk_fp8_f32(vy[0]*iy, vy[1]*iy, 0, false);
  py0     = __builtin_amdgcn_cvt_pk_fp8_f32(vy[2]*iy, vy[3]*iy, py0, true);
  int py1 = __builtin_amdgcn_cvt_pk_fp8_f32(vy[4]*iy, vy[5]*iy, 0, false);
  py1     = __builtin_amdgcn_cvt_pk_fp8_f32(vy[6]*iy, vy[7]*iy, py1, true);
  int2 ox; ox.x = px0; ox.y = px1;
  int2 oy; oy.x = py0; oy.y = py1;
  *(int2*)(Xq + (size_t)row * DIM + tid * 8) = ox;
  *(int2*)(Yq + (size_t)row * DIM + tid * 8) = oy;
  if (tid == 0) dg[row] = xy / (nx * ny);
}

// ---------- kernel 2: 128x128-tile MX-fp8 GEMM, double-buffered 2-phase pipeline ----------
// Per K-step: issue STAGE(t+1)->buf[(t+1)&1], ds_read frags from buf[t&1],
// 16 mfma_scale, s_waitcnt vmcnt(0), ONE s_barrier. Stage latency hides under
// the ds_read+MFMA phase (T3 minimum-2-phase). Hazard: STAGE(t+1) writes the
// buffer last read at iter t-1; those reads were consumed before the
// end-of-(t-1) barrier which precedes this stage -> WAR safe, single barrier.
// LDS swizzle unchanged from round 4 (rule #21): phys 16B chunk p of row r
// holds logical chunk p ^ (r&7); inverse on global source, forward on ds_read.
__global__ void __launch_bounds__(256) k_gemm(const unsigned char* __restrict__ Xq,
                                              const unsigned char* __restrict__ Yq,
                                              float* __restrict__ rowpart,
                                              float* __restrict__ colpart) {
  // bijective XCD swizzle (nwg = 4096, divisible by 8)
  const int wgid = ((int)blockIdx.x & 7) * ((NTILE * NTILE) >> 3) + ((int)blockIdx.x >> 3);
  const int bm = wgid & (NTILE - 1);
  const int bn = wgid >> 6;
  const int tileRow = bm * 128;
  const int tileCol = bn * 128;

  // [buf][A=0/B=1][row][col] : 2 x 32 KiB
  __shared__ __align__(16) unsigned char lds[2][2][128][BK];
  __shared__ float rsum2[2][128];
  __shared__ float csum2[2][128];

  const int tid = threadIdx.x;
  const int lane = tid & 63;
  const int w = tid >> 6;        // wave 0..3
  const int wr = w >> 1;         // wave row 0..1  (64-row sub-tile)
  const int wc = w & 1;          // wave col 0..1  (64-col sub-tile)
  const int lo = lane & 15;
  const int hi = lane >> 4;

  f32x4 acc[4][4];
#pragma unroll
  for (int m = 0; m < 4; ++m)
#pragma unroll
    for (int n = 0; n < 4; ++n) acc[m][n] = (f32x4){0.f, 0.f, 0.f, 0.f};

  // staging: wave w covers rows [w*32, w*32+32), 8 rows per issue, 4 issues.
  // lane l: row +(l>>3), physical chunk l&7 -> logical chunk (l&7)^(l>>3).
  const size_t lrow = (size_t)(lane >> 3);
  const int    lcol = (((lane & 7) ^ (lane >> 3)) * 16);
  const unsigned char* gxa = Xq + ((size_t)(tileRow + w * 32) + lrow) * DIM + lcol;
  const unsigned char* gyb = Yq + ((size_t)(tileCol + w * 32) + lrow) * DIM + lcol;

#define STAGE(tt, bi) do {                                                            \
    const int kb_ = (tt) * BK;                                                        \
    _Pragma("unroll")                                                                 \
    for (int i_ = 0; i_ < 4; ++i_) {                                                  \
      __builtin_amdgcn_global_load_lds(                                               \
          (const __attribute__((address_space(1))) void*)(gxa + (size_t)i_ * 8 * DIM + kb_), \
          (__attribute__((address_space(3))) void*)&lds[bi][0][w * 32 + i_ * 8][0],   \
          16, 0, 0);                                                                  \
      __builtin_amdgcn_global_load_lds(                                               \
          (const __attribute__((address_space(1))) void*)(gyb + (size_t)i_ * 8 * DIM + kb_), \
          (__attribute__((address_space(3))) void*)&lds[bi][1][w * 32 + i_ * 8][0],   \
          16, 0, 0);                                                                  \
    }                                                                                 \
  } while (0)

  // prologue: tile 0 into buf 0
  STAGE(0, 0);
  asm volatile("s_waitcnt vmcnt(0)" ::: "memory");
  __builtin_amdgcn_s_barrier();
  __builtin_amdgcn_sched_barrier(0);

  for (int t = 0; t < KSTEPS; ++t) {
    if (t + 1 < KSTEPS) STAGE(t + 1, (t + 1) & 1);

    // fragment reads: lane holds k = hi*32 .. +31 of its row -> logical chunks
    // 2*hi, 2*hi+1; physical chunk = c ^ (row&7), row&7 = lo&7.
    union Frag { i32x4 q[2]; i32x8 v; };
    Frag a[4], b[4];
#pragma unroll
    for (int m = 0; m < 4; ++m) {
      const unsigned char* r = &lds[t & 1][0][wr * 64 + m * 16 + lo][0];
      a[m].q[0] = *(const i32x4*)(r + (((hi * 2    ) ^ (lo & 7)) * 16));
      a[m].q[1] = *(const i32x4*)(r + (((hi * 2 + 1) ^ (lo & 7)) * 16));
    }
#pragma unroll
    for (int n = 0; n < 4; ++n) {
      const unsigned char* r = &lds[t & 1][1][wc * 64 + n * 16 + lo][0];
      b[n].q[0] = *(const i32x4*)(r + (((hi * 2    ) ^ (lo & 7)) * 16));
      b[n].q[1] = *(const i32x4*)(r + (((hi * 2 + 1) ^ (lo & 7)) * 16));
    }

#pragma unroll
    for (int m = 0; m < 4; ++m)
#pragma unroll
      for (int n = 0; n < 4; ++n)
        acc[m][n] = __builtin_amdgcn_mfma_scale_f32_16x16x128_f8f6f4(
            a[m].v, b[n].v, acc[m][n],
            0, 0,                 // cbsz/blgp = fp8 e4m3
            0, SCALE_I32,
            0, SCALE_I32);

    // loads for tile t+1 had the whole ds_read+MFMA phase to complete
    asm volatile("s_waitcnt vmcnt(0)" ::: "memory");
    __builtin_amdgcn_s_barrier();
    __builtin_amdgcn_sched_barrier(0);
  }
#undef STAGE

  // ---- epilogue: exp + per-tile row/col sums ----
  // D layout (16x16 shapes): row = m*16 + hi*4 + q, col = n*16 + lo
  float rp[4][4];
  float cp[4];
#pragma unroll
  for (int m = 0; m < 4; ++m)
#pragma unroll
    for (int q = 0; q < 4; ++q) rp[m][q] = 0.f;
#pragma unroll
  for (int n = 0; n < 4; ++n) cp[n] = 0.f;

#pragma unroll
  for (int m = 0; m < 4; ++m)
#pragma unroll
    for (int n = 0; n < 4; ++n)
#pragma unroll
      for (int q = 0; q < 4; ++q) {
        float e = __expf(acc[m][n][q]);
        rp[m][q] += e;
        cp[n] += e;
      }

#pragma unroll
  for (int m = 0; m < 4; ++m)
#pragma unroll
    for (int q = 0; q < 4; ++q) {
      float v = rp[m][q];
      v += __shfl_xor(v, 1);
      v += __shfl_xor(v, 2);
      v += __shfl_xor(v, 4);
      v += __shfl_xor(v, 8);
      rp[m][q] = v;
    }
#pragma unroll
  for (int n = 0; n < 4; ++n) {
    float v = cp[n];
    v += __shfl_xor(v, 16);
    v += __shfl_xor(v, 32);
    cp[n] = v;
  }

  if (lo == 0) {
#pragma unroll
    for (int m = 0; m < 4; ++m)
#pragma unroll
      for (int q = 0; q < 4; ++q)
        rsum2[wc][wr * 64 + m * 16 + hi * 4 + q] = rp[m][q];
  }
  if (hi == 0) {
#pragma unroll
    for (int n = 0; n < 4; ++n)
      csum2[wr][wc * 64 + n * 16 + lo] = cp[n];
  }
  __syncthreads();

  if (tid < 128) {
    rowpart[(size_t)bn * BSZ + tileRow + tid] = rsum2[0][tid] + rsum2[1][tid];
    colpart[(size_t)bm * BSZ + tileCol + tid] = csum2[0][tid] + csum2[1][tid];
  }
}

// ---------- kernel 3: reduce partials + final expression ----------
__global__ void __launch_bounds__(256) k_final(const float* __restrict__ rowpart,
                                               const float* __restrict__ colpart,
                                               const float* __restrict__ dg,
                                               float* __restrict__ out) {
  const int k = blockIdx.x * 256 + threadIdx.x;
  float rs = 0.f, cs = 0.f;
#pragma unroll 8
  for (int s = 0; s < NTILE; ++s) {
    rs += rowpart[(size_t)s * BSZ + k];
    cs += colpart[(size_t)s * BSZ + k];
  }
  float d = dg[k];
  float p = __expf(d);
  out[k] = logf(cs - p) + logf(rs - p) - 2.0f * d;
}

extern "C" void kernel_launch(void* const* d_in, const int* in_sizes, int n_in,
                              void* d_out, int out_size, void* d_ws, size_t ws_size,
                              hipStream_t stream) {
  const float* X = (const float*)d_in[0];
  const float* Y = (const float*)d_in[1];
  float* out = (float*)d_out;

  char* ws = (char*)d_ws;
  // layout: Xq (16MB) | Yq (16MB) | diag (32KB) | rowpart (2MB) | colpart (2MB)
  unsigned char* Xq = (unsigned char*)ws;
  unsigned char* Yq = (unsigned char*)(ws + (size_t)BSZ * DIM);
  float* diag = (float*)(ws + (size_t)BSZ * DIM * 2);
  float* rowpart = (float*)(ws + (size_t)BSZ * DIM * 2 + BSZ * 4);
  float* colpart = (float*)(ws + (size_t)BSZ * DIM * 2 + BSZ * 4 + (size_t)NTILE * BSZ * 4);

  k_prep<<<BSZ, 256, 0, stream>>>(X, Y, Xq, Yq, diag);
  k_gemm<<<NTILE * NTILE, 256, 0, stream>>>(Xq, Yq, rowpart, colpart);
  k_final<<<BSZ / 256, 256, 0, stream>>>(rowpart, colpart, diag, out);
}